// Round 1
// baseline (268.065 us; speedup 1.0000x reference)
//
#include <hip/hip_runtime.h>
#include <hip/hip_bf16.h>

// Problem: MLP_AE_72756745994415
// Stage A: x[512,512] -> Linear(512,256)+LeakyReLU -> Linear(256,55) -> 6 group softmaxes -> x3[512,55]
// Stage B: out[k,i] = x3[k,nd] * prod over leading digits of i (last digit dropped), i in [0,99999)
//
// Stage B is the whole game: 205 MB of fp32 writes -> HBM-write-bound (~33 us floor).

#define BATCH 512
#define DIM   512
#define HID   256
#define NCLS  55
#define NOUT  99999
#define RPB   4     // batch rows per block in the MLP kernel
#define LEAK  0.01f

__global__ __launch_bounds__(256) void mlp_x3_kernel(
    const float* __restrict__ x,  const float* __restrict__ w2,
    const float* __restrict__ b2, const float* __restrict__ w3,
    const float* __restrict__ b3, float* __restrict__ x3out) {
    __shared__ float xs[RPB][DIM];   // 8 KB
    __shared__ float hs[RPB][HID];   // 4 KB
    __shared__ float zs[RPB][NCLS];

    const int tid = threadIdx.x;
    const int k0  = blockIdx.x * RPB;

    // stage x rows into LDS (coalesced)
    for (int idx = tid; idx < RPB * DIM; idx += 256) {
        int r = idx >> 9;          // idx / 512
        int d = idx & (DIM - 1);   // idx % 512
        xs[r][d] = x[(k0 + r) * DIM + d];
    }
    __syncthreads();

    // layer 1: thread t computes h[r][t] for r=0..3.
    // w2 row t is streamed sequentially per-thread (L1 retains the live lines).
    float acc[RPB];
#pragma unroll
    for (int r = 0; r < RPB; ++r) acc[r] = 0.f;
    const float* w2row = w2 + tid * DIM;
#pragma unroll 4
    for (int d = 0; d < DIM; ++d) {
        float w = w2row[d];
#pragma unroll
        for (int r = 0; r < RPB; ++r) acc[r] += w * xs[r][d];
    }
    float bb = b2[tid];
#pragma unroll
    for (int r = 0; r < RPB; ++r) {
        float hv = acc[r] + bb;
        hs[r][tid] = (hv >= 0.f) ? hv : LEAK * hv;
    }
    __syncthreads();

    // layer 2: 220 threads, each one (row, out) dot product of length 256
    if (tid < RPB * NCLS) {
        int r = tid / NCLS, o = tid % NCLS;
        const float* w3row = w3 + o * HID;
        float a = b3[o];
#pragma unroll 4
        for (int d = 0; d < HID; ++d) a += hs[r][d] * w3row[d];
        zs[r][o] = a;
    }
    __syncthreads();

    // softmax: 24 threads, each one (row, group). group 0 = len 5, groups 1..5 = len 10.
    if (tid < RPB * 6) {
        int r = tid / 6, g = tid % 6;
        int off = (g == 0) ? 0 : 5 + 10 * (g - 1);
        int len = (g == 0) ? 5 : 10;
        float m = -1e30f;
        for (int u = 0; u < len; ++u) m = fmaxf(m, zs[r][off + u]);
        float s = 0.f;
        for (int u = 0; u < len; ++u) {
            float e = __expf(zs[r][off + u] - m);
            zs[r][off + u] = e;
            s += e;
        }
        float inv = 1.f / s;
        float* orow = x3out + (k0 + r) * NCLS + off;
        for (int u = 0; u < len; ++u) orow[u] = zs[r][off + u] * inv;
    }
}

// Stage B: flat expansion. Each thread produces 4 consecutive flat elements
// (one aligned float4 store). total = 512*99999 = 51,199,488 = 4 * 12,799,872.
__global__ __launch_bounds__(256) void expand_kernel(
    const float* __restrict__ x3, float* __restrict__ out, int ngroups) {
    int g = blockIdx.x * 256 + threadIdx.x;
    if (g >= ngroups) return;
    unsigned e0 = (unsigned)g * 4u;
    float vv[4];
#pragma unroll
    for (int u = 0; u < 4; ++u) {
        unsigned e = e0 + (unsigned)u;
        unsigned k = e / 99999u;          // magic-mul const division
        unsigned i = e - k * 99999u;
        const float* row = x3 + k * (unsigned)NCLS;
        unsigned nd = (i >= 10u) + (i >= 100u) + (i >= 1000u) + (i >= 10000u);
        if (i == 0u) nd = 1u;             // reference special-cases i==0 -> ndig 1 (digit 0)
        float v;
        unsigned d1, d2, d3, d4, r;
        switch (nd) {
            case 0:                        // i in 1..9: lead prob only
                v = row[0];
                break;
            case 1:                        // i in {0} u 10..99
                d1 = i / 10u;
                v = row[1] * row[5 + d1];
                break;
            case 2:
                d2 = i / 100u; r = i - d2 * 100u; d1 = r / 10u;
                v = row[2] * row[5 + d2] * row[15 + d1];
                break;
            case 3:
                d3 = i / 1000u; r = i - d3 * 1000u;
                d2 = r / 100u; r -= d2 * 100u; d1 = r / 10u;
                v = row[3] * row[5 + d3] * row[15 + d2] * row[25 + d1];
                break;
            default:                       // nd == 4, i in 10000..99998
                d4 = i / 10000u; r = i - d4 * 10000u;
                d3 = r / 1000u; r -= d3 * 1000u;
                d2 = r / 100u;  r -= d2 * 100u;  d1 = r / 10u;
                v = row[4] * row[5 + d4] * row[15 + d3] * row[25 + d2] * row[35 + d1];
                break;
        }
        vv[u] = v;
    }
    float4 res = make_float4(vv[0], vv[1], vv[2], vv[3]);
    ((float4*)out)[g] = res;
}

extern "C" void kernel_launch(void* const* d_in, const int* in_sizes, int n_in,
                              void* d_out, int out_size, void* d_ws, size_t ws_size,
                              hipStream_t stream) {
    const float* x  = (const float*)d_in[0];
    const float* w2 = (const float*)d_in[1];
    const float* b2 = (const float*)d_in[2];
    const float* w3 = (const float*)d_in[3];
    const float* b3 = (const float*)d_in[4];
    float* out = (float*)d_out;
    float* x3  = (float*)d_ws;   // 512*55*4 = 112,640 B

    mlp_x3_kernel<<<BATCH / RPB, 256, 0, stream>>>(x, w2, b2, w3, b3, x3);

    const int ngroups = (BATCH * NOUT) / 4;   // 12,799,872, exact
    expand_kernel<<<(ngroups + 255) / 256, 256, 0, stream>>>(x3, out, ngroups);
}

// Round 2
// 243.974 us; speedup vs baseline: 1.0987x; 1.0987x over previous
//
#include <hip/hip_runtime.h>
#include <hip/hip_bf16.h>

// Problem: MLP_AE_72756745994415
// Fully fused: one block per batch row k (512 blocks).
// Phase 1 (per block, ~300 KFLOP): x[k] -> Linear(512,256)+LeakyReLU ->
//   Linear(256,55) -> 6 group softmaxes -> x3s[55] in LDS.
// Phase 2: build pair-product tables in LDS:
//   PP(q)  = x3[5+q/10]*x3[15+q%10]            (top-2-digit product)
//   T4A[q] = x3[4]*PP(q), T3A[q]=x3[3]*PP(q), T2A[q]=x3[2]*PP(q)
//   B4[r]  = x3[25+r/10]*x3[35+r%10]           (digit positions 2,3)
//   B3[d]  = x3[25+d],  A1x[d] = x3[1]*x3[5+d]
// Phase 3: stream 99,999 fp32 per row:
//   i>=10000: T4A[i/1000]*B4[(i/10)%100]
//   i>= 1000: T3A[i/100]*B3[(i/10)%10]
//   i>=  100: T2A[i/10]
//   i>=10 or i==0: A1x[i/10]
//   else: x3[0]
// 205 MB of writes -> HBM-write-bound (~33 us floor).

#define BATCH 512
#define DIM   512
#define HID   256
#define NCLS  55
#define NOUT  99999
#define LEAK  0.01f

__device__ __forceinline__ float digit_factor(
    unsigned i, const float* __restrict__ T4A, const float* __restrict__ T3A,
    const float* __restrict__ T2A, const float* __restrict__ B4,
    const float* __restrict__ B3, const float* __restrict__ A1x, float row0) {
    if (i >= 10000u) {
        unsigned t = i / 10u;          // < 10000
        unsigned q = t / 100u;         // i/1000  in [10,100)
        unsigned r = t - q * 100u;     // (i/10)%100
        return T4A[q] * B4[r];
    } else if (i >= 1000u) {
        unsigned t = i / 10u;          // < 1000
        unsigned q = t / 10u;          // i/100 in [10,100)
        unsigned d = t - q * 10u;      // (i/10)%10
        return T3A[q] * B3[d];
    } else if (i >= 100u) {
        return T2A[i / 10u];           // [10,100)
    } else if (i >= 10u || i == 0u) {
        return A1x[i / 10u];           // i==0 -> A1x[0] (reference special case)
    }
    return row0;                       // i in 1..9
}

__global__ __launch_bounds__(256) void fused_mlp_expand(
    const float* __restrict__ x,  const float* __restrict__ w2,
    const float* __restrict__ b2, const float* __restrict__ w3,
    const float* __restrict__ b3, float* __restrict__ out) {
    __shared__ float xs[DIM];
    __shared__ float hs[HID];
    __shared__ float zp[4][NCLS];
    __shared__ float x3s[NCLS];
    __shared__ float T4A[100], T3A[100], T2A[100], B4[100];
    __shared__ float B3[10], A1x[10];

    const int tid = threadIdx.x;
    const int k   = blockIdx.x;

    // ---- stage x row (coalesced) ----
    xs[tid]       = x[(size_t)k * DIM + tid];
    xs[tid + 256] = x[(size_t)k * DIM + tid + 256];
    __syncthreads();

    // ---- layer 1: thread t computes neuron t, float4 streams ----
    {
        const float4* w2r = (const float4*)(w2 + (size_t)tid * DIM);
        const float4* xr  = (const float4*)xs;
        float acc = 0.f;
#pragma unroll 8
        for (int d4 = 0; d4 < DIM / 4; ++d4) {
            float4 w  = w2r[d4];
            float4 xv = xr[d4];   // LDS broadcast (same addr all lanes)
            acc += w.x * xv.x + w.y * xv.y + w.z * xv.z + w.w * xv.w;
        }
        acc += b2[tid];
        hs[tid] = (acc >= 0.f) ? acc : LEAK * acc;
    }
    __syncthreads();

    // ---- layer 2: 220 threads, split-K (4 parts x 64) ----
    if (tid < 4 * NCLS) {
        int o = tid % NCLS, part = tid / NCLS;
        const float4* w3r = (const float4*)(w3 + (size_t)o * HID + part * 64);
        const float4* hr  = (const float4*)(hs + part * 64);
        float a = 0.f;
#pragma unroll
        for (int d4 = 0; d4 < 16; ++d4) {
            float4 w = w3r[d4];
            float4 h = hr[d4];
            a += w.x * h.x + w.y * h.y + w.z * h.z + w.w * h.w;
        }
        zp[part][o] = a;
    }
    __syncthreads();
    if (tid < NCLS)
        x3s[tid] = zp[0][tid] + zp[1][tid] + zp[2][tid] + zp[3][tid] + b3[tid];
    __syncthreads();

    // ---- softmax: 6 groups (len 5, then 5x len 10) ----
    if (tid < 6) {
        int off = (tid == 0) ? 0 : 5 + 10 * (tid - 1);
        int len = (tid == 0) ? 5 : 10;
        float m = -1e30f;
        for (int u = 0; u < len; ++u) m = fmaxf(m, x3s[off + u]);
        float s = 0.f;
        for (int u = 0; u < len; ++u) {
            float e = __expf(x3s[off + u] - m);
            x3s[off + u] = e;
            s += e;
        }
        float inv = 1.f / s;
        for (int u = 0; u < len; ++u) x3s[off + u] *= inv;
    }
    __syncthreads();

    // ---- build tables ----
    for (int q = tid; q < 100; q += 256) {
        int hi = q / 10, lo = q % 10;
        float pp = x3s[5 + hi] * x3s[15 + lo];
        T4A[q] = x3s[4] * pp;
        T3A[q] = x3s[3] * pp;
        T2A[q] = x3s[2] * pp;
        B4[q]  = x3s[25 + hi] * x3s[35 + lo];
    }
    if (tid < 10) {
        B3[tid]  = x3s[25 + tid];
        A1x[tid] = x3s[1] * x3s[5 + tid];
    }
    __syncthreads();

    const float row0 = x3s[0];

    // ---- write phase: head scalars, aligned float4 body, tail scalars ----
    const size_t base = (size_t)k * NOUT;
    const unsigned head = (unsigned)((4 - (base & 3)) & 3);
    const unsigned ng = (NOUT - head) >> 2;
    const unsigned tail_start = head + (ng << 2);

    if (tid < (int)head)
        out[base + tid] = digit_factor((unsigned)tid, T4A, T3A, T2A, B4, B3, A1x, row0);
    if (tid < (int)(NOUT - tail_start)) {
        unsigned i = tail_start + (unsigned)tid;
        out[base + i] = digit_factor(i, T4A, T3A, T2A, B4, B3, A1x, row0);
    }

    float4* outv = (float4*)(out + base + head);   // 16B-aligned by construction
    for (unsigned g = tid; g < ng; g += 256) {
        unsigned i0 = head + (g << 2);
        float4 v;
        v.x = digit_factor(i0,      T4A, T3A, T2A, B4, B3, A1x, row0);
        v.y = digit_factor(i0 + 1u, T4A, T3A, T2A, B4, B3, A1x, row0);
        v.z = digit_factor(i0 + 2u, T4A, T3A, T2A, B4, B3, A1x, row0);
        v.w = digit_factor(i0 + 3u, T4A, T3A, T2A, B4, B3, A1x, row0);
        outv[g] = v;
    }
}

extern "C" void kernel_launch(void* const* d_in, const int* in_sizes, int n_in,
                              void* d_out, int out_size, void* d_ws, size_t ws_size,
                              hipStream_t stream) {
    const float* x  = (const float*)d_in[0];
    const float* w2 = (const float*)d_in[1];
    const float* b2 = (const float*)d_in[2];
    const float* w3 = (const float*)d_in[3];
    const float* b3 = (const float*)d_in[4];
    float* out = (float*)d_out;

    fused_mlp_expand<<<BATCH, 256, 0, stream>>>(x, w2, b2, w3, b3, out);
}